// Round 16
// baseline (70.363 us; speedup 1.0000x reference)
//
#include <hip/hip_runtime.h>

#define GAMMA 0.1f

constexpr int MTOT = 65536;
constexpr int NTOT = 1024;
constexpr int KDIM = 64;
constexpr int RPB  = 256;   // rows per block; grid = 256 = exactly 1 block/CU

using f16x8 = __attribute__((ext_vector_type(8))) _Float16;  // MFMA A/B frag
using f32x4 = __attribute__((ext_vector_type(4))) float;     // MFMA C/D

typedef __attribute__((address_space(1))) const unsigned int gu32;
typedef __attribute__((address_space(3))) unsigned int lu32;

// ---------------- workspace layout (bytes) ----------------
constexpr size_t WS_CEN = 0;        // 1024*64 fp16 = 131072 (pre-swizzled)
constexpr size_t WS_CSQ = 131072;   // 1024 f32 = 4096
// ws proven >= 17 MB in R2; we need 135 KB.

// ======== kernel 1 (R12-verified pattern): centers f32 -> fp16 pre-swizzled + csq ========
__global__ __launch_bounds__(256)
void cen_convert_kernel(const float* __restrict__ centers,
                        _Float16* __restrict__ cen,
                        float* __restrict__ sq) {
  const int c = blockIdx.x * 256 + threadIdx.x;   // 0..8191
  const int row = c >> 3;
  const int s = c & 7;
  const float4* p = reinterpret_cast<const float4*>(centers + (size_t)row * KDIM + s * 8);
  float4 v0 = p[0], v1 = p[1];
  const float v[8] = {v0.x, v0.y, v0.z, v0.w, v1.x, v1.y, v1.z, v1.w};
  f16x8 hv;
  float ss = 0.0f;
  #pragma unroll
  for (int i = 0; i < 8; ++i) {
    hv[i] = (_Float16)v[i];          // RNE
    ss += v[i] * v[i];               // norms from exact f32
  }
  ss += __shfl_xor(ss, 1);
  ss += __shfl_xor(ss, 2);
  ss += __shfl_xor(ss, 4);
  if (s == 0) sq[row] = ss;
  const int slot = s ^ (row & 7);    // bake LDS bank swizzle into ws layout
  *reinterpret_cast<f16x8*>(cen + (size_t)row * KDIM + slot * 8) = hv;
}

// ======== kernel 2: barrier-free sweep (R15 structure) with DMA'd fp16 centers ========
__global__ __launch_bounds__(1024, 4)
void rbf_sweep_kernel(const float* __restrict__ x,
                      const _Float16* __restrict__ cen,
                      const float* __restrict__ csq,
                      float* __restrict__ out) {
  __shared__ _Float16 sCen[NTOT * KDIM];      // 128 KB, read-only after prologue
  __shared__ float    sCsq[NTOT];             // 4 KB
  // 132 KB -> 1 block/CU (16 waves)

  const int tid = threadIdx.x;
  const int mb = blockIdx.x;                  // 0..255
  const int lane = tid & 63;
  const int wave = tid >> 6;                  // 0..15
  const int l = lane & 15;
  const int g = lane >> 4;                    // k-group 0..3

  // ---- issue this wave's x rows FIRST (latency hidden under centers DMA) ----
  // Lane (g,l) owns x-row (wave*16+l), k-elems ks*32+g*8..+8 (R8..R15-verified).
  const float* xrp = x + ((size_t)mb * RPB + wave * 16 + l) * KDIM;
  float4 xr[4];
  #pragma unroll
  for (int ks = 0; ks < 2; ++ks) {
    xr[ks * 2]     = *reinterpret_cast<const float4*>(xrp + ks * 32 + g * 8);
    xr[ks * 2 + 1] = *reinterpret_cast<const float4*>(xrp + ks * 32 + g * 8 + 4);
  }

  // ---- centers fp16 DMA: 8192 x 16B chunks, linear (swizzle pre-baked in ws) ----
  {
    const char* src = reinterpret_cast<const char*>(cen);
    char* dst = reinterpret_cast<char*>(sCen);
    #pragma unroll
    for (int p = 0; p < 8; ++p) {
      const int q = p * 1024 + tid;
      __builtin_amdgcn_global_load_lds((gu32*)(src + (size_t)q * 16),
                                       (lu32*)(dst + (size_t)q * 16), 16, 0, 0);
    }
  }
  if (tid < 256) {                            // csq DMA (R12-verified pattern)
    __builtin_amdgcn_global_load_lds(
        (gu32*)(reinterpret_cast<const char*>(csq) + (size_t)tid * 16),
        (lu32*)(reinterpret_cast<char*>(sCsq) + (size_t)tid * 16), 16, 0, 0);
  }
  __syncthreads();   // the ONLY barrier (drains DMA + x loads)

  // ---- convert x to B-fragments + full row norm (lane-local) ----
  f16x8 xh[2];
  float ss = 0.0f;
  #pragma unroll
  for (int ks = 0; ks < 2; ++ks) {
    const float v[8] = {xr[ks*2].x,   xr[ks*2].y,   xr[ks*2].z,   xr[ks*2].w,
                        xr[ks*2+1].x, xr[ks*2+1].y, xr[ks*2+1].z, xr[ks*2+1].w};
    f16x8 h;
    #pragma unroll
    for (int e = 0; e < 8; ++e) {
      h[e] = (_Float16)v[e];
      ss += v[e] * v[e];
    }
    xh[ks] = h;
  }
  ss += __shfl_xor(ss, 16);
  ss += __shfl_xor(ss, 32);
  const float nxs = -GAMMA * ss;              // hoisted epilogue term

  // slots are lane-constant: hoist both
  const int slot0 = g ^ (l & 7);
  const int slot1 = (4 + g) ^ (l & 7);

  // ---- barrier-free sweep: 64 col-groups x {2 MFMA, 3-op finish, float4 store} ----
  // out = exp(-g*max(xsq+csq-2acc, 0)) == min(exp(2g*acc - g*(xsq+csq)), 1)
  // (l2<0 -> exp>1 -> clamped to exactly 1, matching max-then-exp).
  float* orow = out + ((size_t)mb * RPB + wave * 16 + l) * (size_t)NTOT;
  #pragma unroll 16
  for (int nf = 0; nf < 64; ++nf) {
    const int crow = nf * 16 + l;             // crow&7 == l&7
    f32x4 acc = {};
    acc = __builtin_amdgcn_mfma_f32_16x16x32_f16(
        *reinterpret_cast<const f16x8*>(&sCen[crow * KDIM + slot0 * 8]), xh[0], acc, 0, 0, 0);
    acc = __builtin_amdgcn_mfma_f32_16x16x32_f16(
        *reinterpret_cast<const f16x8*>(&sCen[crow * KDIM + slot1 * 8]), xh[1], acc, 0, 0, 0);
    const float4 cs = *reinterpret_cast<const float4*>(&sCsq[nf * 16 + g * 4]);
    float4 o;
    o.x = fminf(__expf(fmaf(2.0f * GAMMA, acc[0], fmaf(-GAMMA, cs.x, nxs))), 1.0f);
    o.y = fminf(__expf(fmaf(2.0f * GAMMA, acc[1], fmaf(-GAMMA, cs.y, nxs))), 1.0f);
    o.z = fminf(__expf(fmaf(2.0f * GAMMA, acc[2], fmaf(-GAMMA, cs.z, nxs))), 1.0f);
    o.w = fminf(__expf(fmaf(2.0f * GAMMA, acc[3], fmaf(-GAMMA, cs.w, nxs))), 1.0f);
    *reinterpret_cast<float4*>(orow + nf * 16 + g * 4) = o;
  }
}

extern "C" void kernel_launch(void* const* d_in, const int* in_sizes, int n_in,
                              void* d_out, int out_size, void* d_ws, size_t ws_size,
                              hipStream_t stream) {
  (void)in_sizes; (void)n_in; (void)out_size; (void)ws_size;
  const float* x       = (const float*)d_in[0];
  const float* centers = (const float*)d_in[1];
  float* out = (float*)d_out;

  char* ws = (char*)d_ws;
  _Float16* cen = (_Float16*)(ws + WS_CEN);
  float*    csq = (float*)(ws + WS_CSQ);

  cen_convert_kernel<<<32, 256, 0, stream>>>(centers, cen, csq);
  rbf_sweep_kernel<<<MTOT / RPB, 1024, 0, stream>>>(x, cen, csq, out);
}

// Round 17
// 55.567 us; speedup vs baseline: 1.2663x; 1.2663x over previous
//
#include <hip/hip_runtime.h>

#define GAMMA 0.1f

constexpr int MTOT = 65536;
constexpr int NTOT = 1024;
constexpr int KDIM = 64;
constexpr int RPB  = 256;   // rows per block; grid = 256 = exactly 1 block/CU

using f16x8 = __attribute__((ext_vector_type(8))) _Float16;  // MFMA A/B frag
using f32x4 = __attribute__((ext_vector_type(4))) float;     // MFMA C/D

// R15 champion structure (55.7 us), single change: 3-op epilogue algebra.
// Prologue: stage ALL 1024 centers as fp16 (XOR-swizzled) + csq in LDS (one
// __syncthreads). Then each wave owns 16 PRIVATE output rows and sweeps all
// 64 col-groups {2 MFMA -> finish -> float4 store} with NO synchronization.
__global__ __launch_bounds__(1024, 4)
void rbf_sweep_kernel(const float* __restrict__ x,
                      const float* __restrict__ centers,
                      float* __restrict__ out) {
  __shared__ _Float16 sCen[NTOT * KDIM];      // 128 KB, read-only after prologue
  __shared__ float    sCsq[NTOT];             // 4 KB
  // 132 KB -> 1 block/CU (16 waves)

  const int tid = threadIdx.x;
  const int mb = blockIdx.x;                  // 0..255
  const int lane = tid & 63;
  const int wave = tid >> 6;                  // 0..15
  const int l = lane & 15;
  const int g = lane >> 4;                    // k-group 0..3

  // ---- issue this wave's x row-chunk FIRST (hides under centers staging) ----
  // Lane (g,l) owns x-row (wave*16+l), k-elements ks*32+g*8..+8 (R8..R15-verified).
  const float* xrp = x + ((size_t)mb * RPB + wave * 16 + l) * KDIM;
  float4 xr[4];
  #pragma unroll
  for (int ks = 0; ks < 2; ++ks) {
    xr[ks * 2]     = *reinterpret_cast<const float4*>(xrp + ks * 32 + g * 8);
    xr[ks * 2 + 1] = *reinterpret_cast<const float4*>(xrp + ks * 32 + g * 8 + 4);
  }

  // ---- stage ALL centers: f32 -> fp16 LDS (XOR-swizzled) + csq (R15 code) ----
  {
    const float4* cf = reinterpret_cast<const float4*>(centers);
    #pragma unroll
    for (int p = 0; p < 8; ++p) {
      const int c = p * 1024 + tid;           // 8-elem chunk id 0..8191
      const int row = c >> 3;                 // 0..1023
      const int s = c & 7;
      const float4 v0 = cf[c * 2];
      const float4 v1 = cf[c * 2 + 1];
      const float v[8] = {v0.x, v0.y, v0.z, v0.w, v1.x, v1.y, v1.z, v1.w};
      f16x8 hv;
      float ss = 0.0f;
      #pragma unroll
      for (int i = 0; i < 8; ++i) {
        hv[i] = (_Float16)v[i];               // RNE
        ss += v[i] * v[i];                    // norms from exact f32
      }
      ss += __shfl_xor(ss, 1);
      ss += __shfl_xor(ss, 2);
      ss += __shfl_xor(ss, 4);
      if (s == 0) sCsq[row] = ss;
      const int slot = s ^ (row & 7);         // R1-family swizzle (verified)
      *reinterpret_cast<f16x8*>(&sCen[row * KDIM + slot * 8]) = hv;
    }
  }
  __syncthreads();   // the ONLY barrier

  // ---- convert x to B-fragments + full row norm (lane-local) ----
  f16x8 xh[2];
  float ss = 0.0f;
  #pragma unroll
  for (int ks = 0; ks < 2; ++ks) {
    const float v[8] = {xr[ks*2].x,   xr[ks*2].y,   xr[ks*2].z,   xr[ks*2].w,
                        xr[ks*2+1].x, xr[ks*2+1].y, xr[ks*2+1].z, xr[ks*2+1].w};
    f16x8 h;
    #pragma unroll
    for (int e = 0; e < 8; ++e) {
      h[e] = (_Float16)v[e];
      ss += v[e] * v[e];
    }
    xh[ks] = h;
  }
  // reduce across the 4 k-groups: lane (g,l) -> full norm of row (wave*16+l)
  ss += __shfl_xor(ss, 16);
  ss += __shfl_xor(ss, 32);
  const float nxs = -GAMMA * ss;              // hoisted epilogue term

  // ---- barrier-free sweep: 64 col-groups x {2 MFMA, 3-op finish, float4 store} ----
  // out = exp(-g*max(xsq+csq-2acc, 0)) == min(exp(2g*acc - g*csq - g*xsq), 1)
  // (l2<0 -> exp>1 -> clamps to exactly 1.0, matching max-then-exp bitwise).
  float* orow = out + ((size_t)mb * RPB + wave * 16 + l) * (size_t)NTOT;
  #pragma unroll 8
  for (int nf = 0; nf < 64; ++nf) {
    const int crow = nf * 16 + l;             // crow&7 == l&7 (nf*16 = 0 mod 8)
    f32x4 acc = {};
    #pragma unroll
    for (int ks = 0; ks < 2; ++ks) {
      const int slot = (ks * 4 + g) ^ (l & 7);
      const f16x8 ch = *reinterpret_cast<const f16x8*>(&sCen[crow * KDIM + slot * 8]);
      acc = __builtin_amdgcn_mfma_f32_16x16x32_f16(ch, xh[ks], acc, 0, 0, 0);
    }
    const float4 cs = *reinterpret_cast<const float4*>(&sCsq[nf * 16 + g * 4]);
    float4 o;
    o.x = fminf(__expf(fmaf(2.0f * GAMMA, acc[0], fmaf(-GAMMA, cs.x, nxs))), 1.0f);
    o.y = fminf(__expf(fmaf(2.0f * GAMMA, acc[1], fmaf(-GAMMA, cs.y, nxs))), 1.0f);
    o.z = fminf(__expf(fmaf(2.0f * GAMMA, acc[2], fmaf(-GAMMA, cs.z, nxs))), 1.0f);
    o.w = fminf(__expf(fmaf(2.0f * GAMMA, acc[3], fmaf(-GAMMA, cs.w, nxs))), 1.0f);
    *reinterpret_cast<float4*>(orow + nf * 16 + g * 4) = o;
  }
}

extern "C" void kernel_launch(void* const* d_in, const int* in_sizes, int n_in,
                              void* d_out, int out_size, void* d_ws, size_t ws_size,
                              hipStream_t stream) {
  (void)in_sizes; (void)n_in; (void)d_ws; (void)ws_size; (void)out_size;
  const float* x       = (const float*)d_in[0];
  const float* centers = (const float*)d_in[1];
  float* out = (float*)d_out;
  rbf_sweep_kernel<<<MTOT / RPB, 1024, 0, stream>>>(x, centers, out);
}